// Round 2
// baseline (167955.090 us; speedup 1.0000x reference)
//
#include <hip/hip_runtime.h>
#include <hip/hip_cooperative_groups.h>
#include <cstdint>
#include <cstddef>

namespace cg = cooperative_groups;

#define H   1024
#define V   32000
#define L   2048
#define G4  4096      // 4*H
#define NB  256       // blocks (1 per CU)
#define NT  1024      // threads per block (16 waves of 64)
#define RPB (V / NB)  // 125 FC rows per block

__device__ __forceinline__ float wave_reduce_sum(float v) {
    #pragma unroll
    for (int off = 32; off > 0; off >>= 1) v += __shfl_down(v, off);
    return v;
}

__device__ __forceinline__ unsigned long long wave_reduce_max_u64(unsigned long long v) {
    #pragma unroll
    for (int off = 32; off > 0; off >>= 1) {
        const unsigned long long o = __shfl_down(v, off);
        v = (o > v) ? o : v;
    }
    return v;
}

__device__ __forceinline__ float sigmoidf_(float x) {
    return 1.0f / (1.0f + expf(-x));
}

__device__ __forceinline__ float dot4(const float4 w, const float* __restrict__ h, int c) {
    return w.x * h[c] + w.y * h[c + 1] + w.z * h[c + 2] + w.w * h[c + 3];
}

// ---------------------------------------------------------------------------
// Persistent cooperative kernel: all 2047 steps, 2 grid syncs per step.
// Block-local state: c0 (per-thread reg), c1s/u1s/bfc_s (LDS), w_ih0 col (regs).
// Global state: v0 (double-buffered), h1g, keys.
// ---------------------------------------------------------------------------
__global__ __launch_bounds__(NT, 1) void decoder_persistent(
    const int* __restrict__ y, const float* __restrict__ ctx,
    const float* __restrict__ w_ih0, const float* __restrict__ w_hh0,
    const float* __restrict__ b_ih0, const float* __restrict__ b_hh0,
    const float* __restrict__ w_ih1, const float* __restrict__ w_hh1,
    const float* __restrict__ b_ih1, const float* __restrict__ b_hh1,
    const float* __restrict__ w_fc,  const float* __restrict__ b_fc,
    float* __restrict__ out, float* __restrict__ v0g,
    float* __restrict__ h1g, unsigned long long* __restrict__ keys)
{
    cg::grid_group grid = cg::this_grid();

    __shared__ float h0s[H];
    __shared__ float h1s[H];
    __shared__ float g1s[16];
    __shared__ float u1s[16];
    __shared__ float c1s[4];
    __shared__ float bfc_s[RPB];
    __shared__ unsigned long long kred[4];
    __shared__ unsigned long long wkey[16];

    const int b = blockIdx.x, t_ = threadIdx.x;
    const int wave = t_ >> 6, lane = t_ & 63;

    // ------------------- init -------------------
    h0s[t_] = ctx[t_];
    h1s[t_] = ctx[H + t_];
    float c0_reg = ctx[t_];                    // per-thread cell-0 state (block-redundant)
    if (t_ < 4)   c1s[t_]  = ctx[H + b * 4 + t_];
    if (t_ < RPB) bfc_s[t_] = b_fc[b * RPB + t_];

    // w_ih0 column for element j=t_ (constant over steps)
    const float wi0_i = w_ih0[t_];
    const float wi0_f = w_ih0[H + t_];
    const float wi0_g = w_ih0[2 * H + t_];
    const float wi0_o = w_ih0[3 * H + t_];

    // this wave's fixed recurrent row: gate*H + b*4 + jj
    const int rowR = (wave >> 2) * H + b * 4 + (wave & 3);
    const float bias_v0 = b_ih0[rowR] + b_hh0[rowR];
    const float bias_u1 = b_ih1[rowR] + b_hh1[rowR];

    __syncthreads();

    // initial v0 (global, buffer 0) and u1 (LDS) from ctx
    {
        const float* w0r = w_hh0 + (size_t)rowR * H;
        const float* w1r = w_hh1 + (size_t)rowR * H;
        float accV = 0.f, accU = 0.f;
        #pragma unroll
        for (int k = 0; k < 4; k++) {
            const int c = k * 256 + lane * 4;
            accV += dot4(*(const float4*)(w0r + c), h0s, c);
            accU += dot4(*(const float4*)(w1r + c), h1s, c);
        }
        accV = wave_reduce_sum(accV);
        accU = wave_reduce_sum(accU);
        if (lane == 0) {
            v0g[rowR]  = accV + bias_v0;   // buffer 0
            u1s[wave] = accU + bias_u1;
        }
    }
    if (t_ == 0) {
        // seed keys: +inf value bits guarantee winner; payload = y[0]
        keys[b] = (b == 0)
            ? (((unsigned long long)0x7F800000u << 32) |
               (0xFFFFFFFFu - (unsigned int)y[0]))
            : 0ull;
    }
    grid.sync();

    // ------------------- main loop -------------------
    for (int t = 1; t < L; t++) {
        const float* v0_in  = v0g + ((t - 1) & 1) * G4;
        float*       v0_out = v0g + (t & 1) * G4;

        // ---- phase A: token, cell0, layer-1 gates, cell1 ----
        // argmax finalize: 256 keys -> tok (redundant per block)
        {
            unsigned long long k = 0ull;
            if (wave < 4) {
                k = keys[t_];               // t_ < 256 here
                k = wave_reduce_max_u64(k);
                if (lane == 0) kred[wave] = k;
            }
        }
        __syncthreads();
        unsigned long long kk = kred[0];
        kk = (kred[1] > kk) ? kred[1] : kk;
        kk = (kred[2] > kk) ? kred[2] : kk;
        kk = (kred[3] > kk) ? kred[3] : kk;
        const float tok =
            (float)(unsigned int)(0xFFFFFFFFu - (unsigned int)(kk & 0xFFFFFFFFull));

        // cell0 (block-redundant), j = t_
        {
            const float gi = v0_in[t_]         + tok * wi0_i;
            const float gf = v0_in[H + t_]     + tok * wi0_f;
            const float gg = v0_in[2 * H + t_] + tok * wi0_g;
            const float go = v0_in[3 * H + t_] + tok * wi0_o;
            const float i_ = sigmoidf_(gi);
            const float f_ = sigmoidf_(gf);
            const float g_ = tanhf(gg);
            const float o_ = sigmoidf_(go);
            c0_reg = f_ * c0_reg + i_ * g_;
            h0s[t_] = o_ * tanhf(c0_reg);
        }
        __syncthreads();

        // per-wave: g1 row (w_ih1) and next-step v0 row (w_hh0), fused loads
        {
            const float* wA = w_ih1 + (size_t)rowR * H;
            const float* wB = w_hh0 + (size_t)rowR * H;
            float accA = 0.f, accB = 0.f;
            #pragma unroll
            for (int k = 0; k < 4; k++) {
                const int c = k * 256 + lane * 4;
                accA += dot4(*(const float4*)(wA + c), h0s, c);
                accB += dot4(*(const float4*)(wB + c), h0s, c);
            }
            accA = wave_reduce_sum(accA);
            accB = wave_reduce_sum(accB);
            if (lane == 0) {
                g1s[wave]    = accA + u1s[wave];   // + (w_hh1@h1_prev + biases)
                v0_out[rowR] = accB + bias_v0;
            }
        }
        __syncthreads();

        // cell1: this block's 4 elements
        if (t_ < 4) {
            const float i_ = sigmoidf_(g1s[t_]);
            const float f_ = sigmoidf_(g1s[4 + t_]);
            const float g_ = tanhf(g1s[8 + t_]);
            const float o_ = sigmoidf_(g1s[12 + t_]);
            const float cn = f_ * c1s[t_] + i_ * g_;
            c1s[t_] = cn;
            h1g[b * 4 + t_] = o_ * tanhf(cn);
        }
        grid.sync();

        // ---- phase B: FC + argmax keys + next-step u1 ----
        h1s[t_] = h1g[t_];
        __syncthreads();

        unsigned long long bestKey = 0ull;
        float* out_row = out + (size_t)t * V;
        #pragma unroll
        for (int i = 0; i < 8; i++) {
            const int rl = i * 16 + wave;
            if (rl >= RPB) break;
            const int row = b * RPB + rl;
            const float* wrow = w_fc + (size_t)row * H;
            float acc = 0.f;
            #pragma unroll
            for (int k = 0; k < 4; k++) {
                const int c = k * 256 + lane * 4;
                acc += dot4(*(const float4*)(wrow + c), h1s, c);
            }
            acc = wave_reduce_sum(acc);
            if (lane == 0) {
                float p = acc + bfc_s[rl];
                p = p > 0.f ? p : 0.f;
                out_row[row] = p;
                const unsigned long long key =
                    ((unsigned long long)__float_as_uint(p) << 32) |
                    (0xFFFFFFFFu - (unsigned int)row);
                if (key > bestKey) bestKey = key;
            }
        }

        // next-step u1 row for this wave
        {
            const float* wrow = w_hh1 + (size_t)rowR * H;
            float acc = 0.f;
            #pragma unroll
            for (int k = 0; k < 4; k++) {
                const int c = k * 256 + lane * 4;
                acc += dot4(*(const float4*)(wrow + c), h1s, c);
            }
            acc = wave_reduce_sum(acc);
            if (lane == 0) u1s[wave] = acc + bias_u1;
        }

        if (lane == 0) wkey[wave] = bestKey;
        __syncthreads();
        if (t_ == 0) {
            unsigned long long k = wkey[0];
            #pragma unroll
            for (int i = 1; i < 16; i++) k = (wkey[i] > k) ? wkey[i] : k;
            keys[b] = k;
        }
        grid.sync();
    }
}

// ---------------------------------------------------------------------------
// Host launcher
// ---------------------------------------------------------------------------
extern "C" void kernel_launch(void* const* d_in, const int* in_sizes, int n_in,
                              void* d_out, int out_size, void* d_ws, size_t ws_size,
                              hipStream_t stream)
{
    const int*   y     = (const int*)  d_in[0];
    const float* ctx   = (const float*)d_in[1];
    const float* w_ih0 = (const float*)d_in[2];
    const float* w_hh0 = (const float*)d_in[3];
    const float* b_ih0 = (const float*)d_in[4];
    const float* b_hh0 = (const float*)d_in[5];
    const float* w_ih1 = (const float*)d_in[6];
    const float* w_hh1 = (const float*)d_in[7];
    const float* b_ih1 = (const float*)d_in[8];
    const float* b_hh1 = (const float*)d_in[9];
    const float* w_fc  = (const float*)d_in[10];
    const float* b_fc  = (const float*)d_in[11];
    float* out = (float*)d_out;

    char* ws = (char*)d_ws;
    float* v0g = (float*)(ws + 0);                                // [2][4096]
    float* h1g = (float*)(ws + 32768);                            // [1024]
    unsigned long long* keys = (unsigned long long*)(ws + 36864); // [256]

    // out row 0 is defined as zeros
    hipMemsetAsync(d_out, 0, (size_t)V * sizeof(float), stream);

    void* args[] = {
        (void*)&y, (void*)&ctx, (void*)&w_ih0, (void*)&w_hh0,
        (void*)&b_ih0, (void*)&b_hh0, (void*)&w_ih1, (void*)&w_hh1,
        (void*)&b_ih1, (void*)&b_hh1, (void*)&w_fc, (void*)&b_fc,
        (void*)&out, (void*)&v0g, (void*)&h1g, (void*)&keys
    };
    hipLaunchCooperativeKernel((const void*)decoder_persistent,
                               dim3(NB), dim3(NT), args, 0, stream);
}

// Round 3
// 50345.197 us; speedup vs baseline: 3.3361x; 3.3361x over previous
//
#include <hip/hip_runtime.h>
#include <hip/hip_fp16.h>
#include <cstdint>
#include <cstddef>

#define H   1024
#define V   32000
#define L   2048
#define G4  4096      // 4*H
#define NB  256       // blocks
#define NT  1024      // threads per block (16 waves of 64)
#define RPB (V / NB)  // 125 FC rows per block

// ---------------------------------------------------------------------------
__device__ __forceinline__ float wave_reduce_sum(float v) {
    #pragma unroll
    for (int off = 32; off > 0; off >>= 1) v += __shfl_down(v, off);
    return v;
}

__device__ __forceinline__ float wave_reduce_max(float v) {
    #pragma unroll
    for (int off = 32; off > 0; off >>= 1) v = fmaxf(v, __shfl_down(v, off));
    return v;
}

__device__ __forceinline__ unsigned long long wave_reduce_max_u64(unsigned long long v) {
    #pragma unroll
    for (int off = 32; off > 0; off >>= 1) {
        const unsigned long long o = __shfl_down(v, off);
        v = (o > v) ? o : v;
    }
    return v;
}

__device__ __forceinline__ float sigmoidf_(float x) {
    return 1.0f / (1.0f + expf(-x));
}

__device__ __forceinline__ float dot4(const float4 w, const float* __restrict__ h, int c) {
    return w.x * h[c] + w.y * h[c + 1] + w.z * h[c + 2] + w.w * h[c + 3];
}

// ---------------------------------------------------------------------------
// One-time (per launch): w_fc fp32 -> fp16 in workspace
// ---------------------------------------------------------------------------
__global__ __launch_bounds__(256) void convert_fc(
    const float* __restrict__ src, __half* __restrict__ dst, int n2)
{
    const int stride = gridDim.x * blockDim.x;
    for (int i = blockIdx.x * blockDim.x + threadIdx.x; i < n2; i += stride) {
        const float2 f = ((const float2*)src)[i];
        ((__half2*)dst)[i] = __floats2half2_rn(f.x, f.y);
    }
}

// ---------------------------------------------------------------------------
// Init: v0 = w_hh0@h0_init + biases, u1 = w_hh1@h1_init + biases,
//       c0/c1/h1g from ctx, keys seeded with y[0].
// ---------------------------------------------------------------------------
__global__ __launch_bounds__(NT) void init_kernel(
    const int* __restrict__ y, const float* __restrict__ ctx,
    const float* __restrict__ w_hh0, const float* __restrict__ b_ih0,
    const float* __restrict__ b_hh0,
    const float* __restrict__ w_hh1, const float* __restrict__ b_ih1,
    const float* __restrict__ b_hh1,
    float* __restrict__ v0, float* __restrict__ u1,
    float* __restrict__ c0, float* __restrict__ c1,
    float* __restrict__ h1g, unsigned long long* __restrict__ keys)
{
    __shared__ __align__(16) float h0s[H];
    __shared__ __align__(16) float h1s[H];
    const int b = blockIdx.x, t = threadIdx.x;
    h0s[t] = ctx[t];
    h1s[t] = ctx[H + t];
    __syncthreads();

    const int wave = t >> 6, lane = t & 63;
    const int rowR = (wave >> 2) * H + b * 4 + (wave & 3);
    {
        const float* w0r = w_hh0 + (size_t)rowR * H;
        const float* w1r = w_hh1 + (size_t)rowR * H;
        float accV = 0.f, accU = 0.f;
        #pragma unroll
        for (int k = 0; k < 4; k++) {
            const int c = k * 256 + lane * 4;
            accV += dot4(*(const float4*)(w0r + c), h0s, c);
            accU += dot4(*(const float4*)(w1r + c), h1s, c);
        }
        accV = wave_reduce_sum(accV);
        accU = wave_reduce_sum(accU);
        if (lane == 0) {
            v0[rowR] = accV + b_ih0[rowR] + b_hh0[rowR];
            u1[rowR] = accU + b_ih1[rowR] + b_hh1[rowR];
        }
    }
    if (b == 0) {
        c0[t]  = ctx[t];
        c1[t]  = ctx[H + t];
        h1g[t] = ctx[H + t];
        if (t < NB) keys[t] = 0ull;
        if (t == 0) {
            keys[0] = ((unsigned long long)0x7F800000u << 32) |
                      (0xFFFFFFFFu - (unsigned int)y[0]);
        }
    }
}

// ---------------------------------------------------------------------------
// K_A: argmax finalize (redundant), cell0 (redundant), fused w_ih1@h0 /
//      w_hh0@h0 per wave, cell1 for this block's 4 h1 elems.
// ---------------------------------------------------------------------------
__global__ __launch_bounds__(NT) void lstm_kernel(
    const float* __restrict__ w_ih0, const float* __restrict__ w_ih1,
    const float* __restrict__ w_hh0,
    const float* __restrict__ b_ih0, const float* __restrict__ b_hh0,
    const float* __restrict__ v0_in, float* __restrict__ v0_out,
    const float* __restrict__ u1,
    const float* __restrict__ c0_in, float* __restrict__ c0_out,
    float* __restrict__ c1, float* __restrict__ h1g,
    const unsigned long long* __restrict__ keys)
{
    __shared__ __align__(16) float h0s[H];
    __shared__ float g1s[16];
    __shared__ unsigned long long kred[4];
    const int b = blockIdx.x, t = threadIdx.x;
    const int wave = t >> 6, lane = t & 63;

    // 1. argmax finalize over 256 block keys (redundant per block)
    if (wave < 4) {
        unsigned long long k = keys[t];           // t < 256
        k = wave_reduce_max_u64(k);
        if (lane == 0) kred[wave] = k;
    }
    __syncthreads();
    unsigned long long kk = kred[0];
    kk = (kred[1] > kk) ? kred[1] : kk;
    kk = (kred[2] > kk) ? kred[2] : kk;
    kk = (kred[3] > kk) ? kred[3] : kk;
    const float tok =
        (float)(unsigned int)(0xFFFFFFFFu - (unsigned int)(kk & 0xFFFFFFFFull));

    // 2. cell0 (block-redundant), element j = t
    {
        const float gi = v0_in[t]         + tok * w_ih0[t];
        const float gf = v0_in[H + t]     + tok * w_ih0[H + t];
        const float gg = v0_in[2 * H + t] + tok * w_ih0[2 * H + t];
        const float go = v0_in[3 * H + t] + tok * w_ih0[3 * H + t];
        const float i_ = sigmoidf_(gi);
        const float f_ = sigmoidf_(gf);
        const float g_ = tanhf(gg);
        const float o_ = sigmoidf_(go);
        const float cn = f_ * c0_in[t] + i_ * g_;
        if (b == 0) c0_out[t] = cn;
        h0s[t] = o_ * tanhf(cn);
    }
    __syncthreads();

    // 3. per wave: fused g1 row (w_ih1@h0) and next-step v0 row (w_hh0@h0)
    const int rowR = (wave >> 2) * H + b * 4 + (wave & 3);
    {
        const float* wA = w_ih1 + (size_t)rowR * H;
        const float* wB = w_hh0 + (size_t)rowR * H;
        float accA = 0.f, accB = 0.f;
        #pragma unroll
        for (int k = 0; k < 4; k++) {
            const int c = k * 256 + lane * 4;
            accA += dot4(*(const float4*)(wA + c), h0s, c);
            accB += dot4(*(const float4*)(wB + c), h0s, c);
        }
        accA = wave_reduce_sum(accA);
        accB = wave_reduce_sum(accB);
        if (lane == 0) {
            g1s[wave]    = accA + u1[rowR];
            v0_out[rowR] = accB + b_ih0[rowR] + b_hh0[rowR];
        }
    }
    __syncthreads();

    // 4. cell1: this block's 4 elements
    if (t < 4) {
        const float i_ = sigmoidf_(g1s[t]);
        const float f_ = sigmoidf_(g1s[4 + t]);
        const float g_ = tanhf(g1s[8 + t]);
        const float o_ = sigmoidf_(g1s[12 + t]);
        const float cn = f_ * c1[b * 4 + t] + i_ * g_;
        c1[b * 4 + t] = cn;
        h1g[b * 4 + t] = o_ * tanhf(cn);
    }
}

// ---------------------------------------------------------------------------
// K_B: FC from fp16 weights (125 rows/block) + fp32 rescue of near-max rows
//      (exact argmax), relu + out write, per-block argmax key, next-step u1.
// ---------------------------------------------------------------------------
__global__ __launch_bounds__(NT) void fc_kernel(
    const __half* __restrict__ wfc16, const float* __restrict__ w_fc,
    const float* __restrict__ b_fc,
    const float* __restrict__ w_hh1, const float* __restrict__ b_ih1,
    const float* __restrict__ b_hh1,
    const float* __restrict__ h1g, float* __restrict__ u1,
    unsigned long long* __restrict__ keys,
    float* __restrict__ out_row, const int use16)
{
    __shared__ __align__(16) float h1s[H];
    __shared__ float aprx[128];
    __shared__ float Amax_s;
    __shared__ unsigned long long wkey[16];
    const int b = blockIdx.x, t = threadIdx.x;
    const int wave = t >> 6, lane = t & 63;

    h1s[t] = h1g[t];
    if (t < 128) aprx[t] = -1.f;
    __syncthreads();

    unsigned long long bestKey = 0ull;

    if (use16) {
        // ---- pass 1: fp16 approx values, two rows fused for MLP ----
        #pragma unroll
        for (int i = 0; i < 8; i += 2) {
            const int rlA = i * 16 + wave;       // <= 111, always valid
            const int rlB = rlA + 16;
            const bool vB = (rlB < RPB);
            const int rowA = b * RPB + rlA;
            const int rowB = b * RPB + rlB;
            const __half* pA = wfc16 + (size_t)rowA * H;
            const __half* pB = wfc16 + (size_t)rowB * H;
            float aA = 0.f, aB = 0.f;
            #pragma unroll
            for (int k = 0; k < 2; k++) {
                const int e = k * 512 + lane * 8;
                const float4 hv0 = *(const float4*)(h1s + e);
                const float4 hv1 = *(const float4*)(h1s + e + 4);
                const float4 rA = *(const float4*)(pA + e);
                const __half2* ha = (const __half2*)&rA;
                float2 f0 = __half22float2(ha[0]), f1 = __half22float2(ha[1]);
                float2 f2 = __half22float2(ha[2]), f3 = __half22float2(ha[3]);
                aA += f0.x * hv0.x + f0.y * hv0.y + f1.x * hv0.z + f1.y * hv0.w
                    + f2.x * hv1.x + f2.y * hv1.y + f3.x * hv1.z + f3.y * hv1.w;
                if (vB) {
                    const float4 rB = *(const float4*)(pB + e);
                    const __half2* hb = (const __half2*)&rB;
                    float2 g0 = __half22float2(hb[0]), g1 = __half22float2(hb[1]);
                    float2 g2 = __half22float2(hb[2]), g3 = __half22float2(hb[3]);
                    aB += g0.x * hv0.x + g0.y * hv0.y + g1.x * hv0.z + g1.y * hv0.w
                        + g2.x * hv1.x + g2.y * hv1.y + g3.x * hv1.z + g3.y * hv1.w;
                }
            }
            aA = wave_reduce_sum(aA);
            aB = wave_reduce_sum(aB);
            if (lane == 0) {
                float p = aA + b_fc[rowA];
                p = p > 0.f ? p : 0.f;
                out_row[rowA] = p;
                aprx[rlA] = p;
                if (vB) {
                    float q = aB + b_fc[rowB];
                    q = q > 0.f ? q : 0.f;
                    out_row[rowB] = q;
                    aprx[rlB] = q;
                }
            }
        }
        __syncthreads();

        // ---- block approx max ----
        if (wave == 0) {
            float m = fmaxf(aprx[lane], aprx[lane + 64]);
            m = wave_reduce_max(m);
            if (lane == 0) Amax_s = m;
        }
        __syncthreads();
        const float thresh = Amax_s - 0.01f;   // fp16 dot error << 0.005

        // ---- pass 2: fp32 rescue of near-max rows (exact argmax) ----
        #pragma unroll
        for (int i = 0; i < 8; i++) {
            const int rl = i * 16 + wave;
            if (rl >= RPB) break;
            const float av = aprx[rl];          // wave-uniform
            if (av >= thresh) {
                const int row = b * RPB + rl;
                const float* wrow = w_fc + (size_t)row * H;
                float acc = 0.f;
                #pragma unroll
                for (int k = 0; k < 4; k++) {
                    const int c = k * 256 + lane * 4;
                    acc += dot4(*(const float4*)(wrow + c), h1s, c);
                }
                acc = wave_reduce_sum(acc);
                if (lane == 0) {
                    float p = acc + b_fc[row];
                    p = p > 0.f ? p : 0.f;
                    out_row[row] = p;           // exact value
                    const unsigned long long key =
                        ((unsigned long long)__float_as_uint(p) << 32) |
                        (0xFFFFFFFFu - (unsigned int)row);
                    if (key > bestKey) bestKey = key;
                }
            }
        }
    } else {
        // ---- fp32 fallback (R0 path) ----
        #pragma unroll
        for (int i = 0; i < 8; i++) {
            const int rl = i * 16 + wave;
            if (rl >= RPB) break;
            const int row = b * RPB + rl;
            const float* wrow = w_fc + (size_t)row * H;
            float acc = 0.f;
            #pragma unroll
            for (int k = 0; k < 4; k++) {
                const int c = k * 256 + lane * 4;
                acc += dot4(*(const float4*)(wrow + c), h1s, c);
            }
            acc = wave_reduce_sum(acc);
            if (lane == 0) {
                float p = acc + b_fc[row];
                p = p > 0.f ? p : 0.f;
                out_row[row] = p;
                const unsigned long long key =
                    ((unsigned long long)__float_as_uint(p) << 32) |
                    (0xFFFFFFFFu - (unsigned int)row);
                if (key > bestKey) bestKey = key;
            }
        }
    }

    // ---- next-step u1 row for this wave ----
    {
        const int rowR = (wave >> 2) * H + b * 4 + (wave & 3);
        const float* wrow = w_hh1 + (size_t)rowR * H;
        float acc = 0.f;
        #pragma unroll
        for (int k = 0; k < 4; k++) {
            const int c = k * 256 + lane * 4;
            acc += dot4(*(const float4*)(wrow + c), h1s, c);
        }
        acc = wave_reduce_sum(acc);
        if (lane == 0) u1[rowR] = acc + b_ih1[rowR] + b_hh1[rowR];
    }

    if (lane == 0) wkey[wave] = bestKey;
    __syncthreads();
    if (t == 0) {
        unsigned long long k = wkey[0];
        #pragma unroll
        for (int i = 1; i < 16; i++) k = (wkey[i] > k) ? wkey[i] : k;
        keys[b] = k;
    }
}

// ---------------------------------------------------------------------------
// Host launcher
// ---------------------------------------------------------------------------
extern "C" void kernel_launch(void* const* d_in, const int* in_sizes, int n_in,
                              void* d_out, int out_size, void* d_ws, size_t ws_size,
                              hipStream_t stream)
{
    const int*   y     = (const int*)  d_in[0];
    const float* ctx   = (const float*)d_in[1];
    const float* w_ih0 = (const float*)d_in[2];
    const float* w_hh0 = (const float*)d_in[3];
    const float* b_ih0 = (const float*)d_in[4];
    const float* b_hh0 = (const float*)d_in[5];
    const float* w_ih1 = (const float*)d_in[6];
    const float* w_hh1 = (const float*)d_in[7];
    const float* b_ih1 = (const float*)d_in[8];
    const float* b_hh1 = (const float*)d_in[9];
    const float* w_fc  = (const float*)d_in[10];
    const float* b_fc  = (const float*)d_in[11];
    float* out = (float*)d_out;

    const size_t FC16_BYTES = (size_t)V * H * sizeof(__half);   // 65,536,000
    const size_t STATE_BYTES = 67584;
    const int use16 = (ws_size >= FC16_BYTES + STATE_BYTES) ? 1 : 0;

    char* ws = (char*)d_ws;
    __half* wfc16 = (__half*)ws;
    char* base = ws + (use16 ? FC16_BYTES : 0);
    float* v0g = (float*)(base + 0);                                // [2][4096]
    float* u1  = (float*)(base + 32768);                            // [4096]
    float* c0  = (float*)(base + 49152);                            // [2][1024]
    float* c1  = (float*)(base + 57344);                            // [1024]
    float* h1g = (float*)(base + 61440);                            // [1024]
    unsigned long long* keys = (unsigned long long*)(base + 65536); // [256]

    // out row 0 is defined as zeros
    hipMemsetAsync(d_out, 0, (size_t)V * sizeof(float), stream);

    if (use16) {
        convert_fc<<<1024, 256, 0, stream>>>(w_fc, wfc16, V * H / 2);
    }

    init_kernel<<<NB, NT, 0, stream>>>(y, ctx, w_hh0, b_ih0, b_hh0,
                                       w_hh1, b_ih1, b_hh1,
                                       v0g, u1, c0, c1, h1g, keys);

    for (int t = 1; t < L; t++) {
        const float* v0i = v0g + ((t - 1) & 1) * G4;
        float*       v0o = v0g + (t & 1) * G4;
        const float* c0i = c0 + ((t - 1) & 1) * H;
        float*       c0o = c0 + (t & 1) * H;
        lstm_kernel<<<NB, NT, 0, stream>>>(w_ih0, w_ih1, w_hh0, b_ih0, b_hh0,
                                           v0i, v0o, u1, c0i, c0o, c1, h1g, keys);
        fc_kernel<<<NB, NT, 0, stream>>>(wfc16, w_fc, b_fc,
                                         w_hh1, b_ih1, b_hh1,
                                         h1g, u1, keys,
                                         out + (size_t)t * V, use16);
    }
}